// Round 1
// baseline (100.256 us; speedup 1.0000x reference)
//
#include <hip/hip_runtime.h>

// RankNet pairwise loss, N=8192 fp32.
// Tile: 256 j-columns (one per thread) x 64 i-rows (uniform loop).
// Blocks fully below the diagonal exit early (write zero partials).
// Deterministic two-pass reduction through d_ws (no atomics, no memset).

#define TJ 256  // j-tile width == blockDim.x
#define TI 64   // i-rows per block

__global__ __launch_bounds__(TJ) void rank_pairs_kernel(
    const float* __restrict__ pred, const float* __restrict__ target, int n,
    float* __restrict__ part_sum, unsigned int* __restrict__ part_cnt)
{
    const int bid    = blockIdx.y * gridDim.x + blockIdx.x;
    const int j_base = blockIdx.x * TJ;
    const int i_base = blockIdx.y * TI;

    float sum = 0.f;
    unsigned int cnt = 0u;

    // Tile contains at least one pair with i < j iff i_base < j_base + TJ.
    if (i_base < j_base + TJ) {
        const int  j   = j_base + (int)threadIdx.x;
        const bool jin = (j < n);
        const float pj = jin ? pred[j]   : 0.f;
        const float tj = jin ? target[j] : 0.f;

        #pragma unroll 8
        for (int k = 0; k < TI; ++k) {
            const int i = i_base + k;          // block-uniform -> scalar loads
            if (i >= n) break;
            const float ti = target[i];
            const float pi = pred[i];
            const float td = ti - tj;          // t_i - t_j
            const float pd = pi - pj;          // p_i - p_j
            // z = -sign(td) * pd  (td==0 is masked out below)
            const float z  = (td > 0.f) ? -pd : pd;
            const bool valid = jin & (i < j) & (td != 0.f);
            // stable softplus(z) = max(z,0) + log(1 + exp(-|z|))
            const float sp = fmaxf(z, 0.f) + __logf(1.f + __expf(-fabsf(z)));
            sum += valid ? sp : 0.f;
            cnt += valid ? 1u : 0u;
        }
    }

    // wave(64) shuffle reduce, then cross-wave via LDS
    #pragma unroll
    for (int off = 32; off > 0; off >>= 1) {
        sum += __shfl_down(sum, off, 64);
        cnt += __shfl_down(cnt, off, 64);
    }
    __shared__ float        s_s[TJ / 64];
    __shared__ unsigned int s_c[TJ / 64];
    const int lane = threadIdx.x & 63;
    const int wv   = threadIdx.x >> 6;
    if (lane == 0) { s_s[wv] = sum; s_c[wv] = cnt; }
    __syncthreads();
    if (threadIdx.x == 0) {
        float bs = 0.f; unsigned int bc = 0u;
        #pragma unroll
        for (int w = 0; w < TJ / 64; ++w) { bs += s_s[w]; bc += s_c[w]; }
        part_sum[bid] = bs;
        part_cnt[bid] = bc;
    }
}

__global__ __launch_bounds__(256) void finalize_kernel(
    const float* __restrict__ part_sum, const unsigned int* __restrict__ part_cnt,
    int nparts, float* __restrict__ out)
{
    float sum = 0.f;
    unsigned int cnt = 0u;
    for (int idx = (int)threadIdx.x; idx < nparts; idx += 256) {
        sum += part_sum[idx];
        cnt += part_cnt[idx];
    }
    #pragma unroll
    for (int off = 32; off > 0; off >>= 1) {
        sum += __shfl_down(sum, off, 64);
        cnt += __shfl_down(cnt, off, 64);
    }
    __shared__ float        s_s[4];
    __shared__ unsigned int s_c[4];
    const int lane = threadIdx.x & 63;
    const int wv   = threadIdx.x >> 6;
    if (lane == 0) { s_s[wv] = sum; s_c[wv] = cnt; }
    __syncthreads();
    if (threadIdx.x == 0) {
        float bs = s_s[0] + s_s[1] + s_s[2] + s_s[3];
        unsigned int bc = s_c[0] + s_c[1] + s_c[2] + s_c[3];
        out[0] = (bc > 0u) ? bs / (float)bc : 0.f;
    }
}

extern "C" void kernel_launch(void* const* d_in, const int* in_sizes, int n_in,
                              void* d_out, int out_size, void* d_ws, size_t ws_size,
                              hipStream_t stream)
{
    const float* pred   = (const float*)d_in[0];
    const float* target = (const float*)d_in[1];
    float* out = (float*)d_out;
    const int n = in_sizes[0];

    const int gx = (n + TJ - 1) / TJ;   // 32 for n=8192
    const int gy = (n + TI - 1) / TI;   // 128 for n=8192
    const int nparts = gx * gy;         // 4096 partials

    float*        part_sum = (float*)d_ws;
    unsigned int* part_cnt = (unsigned int*)((char*)d_ws + (size_t)nparts * sizeof(float));

    rank_pairs_kernel<<<dim3(gx, gy), TJ, 0, stream>>>(pred, target, n, part_sum, part_cnt);
    finalize_kernel<<<1, 256, 0, stream>>>(part_sum, part_cnt, nparts, out);
}